// Round 16
// baseline (3301.717 us; speedup 1.0000x reference)
//
#include <hip/hip_runtime.h>
#include <stdint.h>

typedef __attribute__((ext_vector_type(8))) short s16x8;
typedef __attribute__((ext_vector_type(4))) float f32x4;

#define CB 2
#define CT 2048
#define CD 1024
#define CNH 16
#define CHD 64
#define CDFF 4096
#define CKB 512

__device__ __forceinline__ short f2bf(float f){
  union { float f; uint32_t u; } v; v.f = f;
  uint32_t r = v.u + 0x7FFFu + ((v.u >> 16) & 1u);
  return (short)(r >> 16);
}
__device__ __forceinline__ float bf2f(short h){
  union { uint32_t u; float f; } v; v.u = ((uint32_t)(uint16_t)h) << 16;
  return v.f;
}
__device__ __forceinline__ uint32_t cvtpk_bf16(float lo, float hi){
  uint32_t r;
  asm("v_cvt_pk_bf16_f32 %0, %1, %2" : "=v"(r) : "v"(lo), "v"(hi));
  return r;
}

#define GLOAD16(g, l) __builtin_amdgcn_global_load_lds( \
    (const __attribute__((address_space(1))) void*)(g), \
    (__attribute__((address_space(3))) void*)(l), 16, 0, 0)

// ---------------- fused gather + residual + RMSNorm ----------------
__global__ void gather_rms_kernel(const float* __restrict__ xp, const int* __restrict__ bnd,
                                  const float* __restrict__ xr, const float* __restrict__ w,
                                  float* __restrict__ x, short* __restrict__ hbuf){
  int row = blockIdx.x;                  // b*2048 + t
  int b = row >> 11, t = row & 2047;
  int tid = threadIdx.x;
  int lo = 0, hi = CKB;
  while (lo < hi){ int mid = (lo + hi) >> 1; if (bnd[b*CKB + mid] <= t) lo = mid + 1; else hi = mid; }
  const float4 s  = ((const float4*)(xp + ((size_t)b*CKB + lo)*CD))[tid];
  const float4 rr = ((const float4*)(xr + (size_t)row*CD))[tid];
  float4 a; a.x = s.x + rr.x; a.y = s.y + rr.y; a.z = s.z + rr.z; a.w = s.w + rr.w;
  ((float4*)(x + (size_t)row*CD))[tid] = a;
  float ss = a.x*a.x + a.y*a.y + a.z*a.z + a.w*a.w;
  #pragma unroll
  for (int m = 1; m < 64; m <<= 1) ss += __shfl_xor(ss, m);
  __shared__ float red[4];
  if ((tid & 63) == 0) red[tid >> 6] = ss;
  __syncthreads();
  float tot = red[0] + red[1] + red[2] + red[3];
  float scale = rsqrtf(tot * (1.0f/1024.0f) + 1e-5f);
  const float4 wv = ((const float4*)w)[tid];
  short4 o;
  o.x = f2bf(a.x*scale*wv.x); o.y = f2bf(a.y*scale*wv.y);
  o.z = f2bf(a.z*scale*wv.z); o.w = f2bf(a.w*scale*wv.w);
  ((short4*)hbuf)[(size_t)row*256 + tid] = o;
}

// ---------------- weight fp32 -> bf16 transposes (merged) ----------------
__global__ void wtrans_qkvo_kernel(const float* __restrict__ wq, const float* __restrict__ wk,
                                   const float* __restrict__ wv, const float* __restrict__ wo,
                                   short* __restrict__ qkvT, short* __restrict__ woT){
  __shared__ __align__(16) float tile[64*65];
  const float* W; short* dst;
  const int z = blockIdx.z;
  if (z == 0){ W = wq; dst = qkvT; }
  else if (z == 1){ W = wk; dst = qkvT + (size_t)1024*1024; }
  else if (z == 2){ W = wv; dst = qkvT + (size_t)2048*1024; }
  else { W = wo; dst = woT; }
  int n0 = blockIdx.x*64, k0 = blockIdx.y*64;
  #pragma unroll
  for (int i = 0; i < 16; ++i){
    int e = threadIdx.x + 256*i; int kl = e >> 6, nl = e & 63;
    tile[kl*65 + nl] = W[(size_t)(k0 + kl)*1024 + n0 + nl];
  }
  __syncthreads();
  #pragma unroll
  for (int i = 0; i < 16; ++i){
    int e = threadIdx.x + 256*i; int nl = e >> 6, kl = e & 63;
    dst[(size_t)(n0 + nl)*1024 + k0 + kl] = f2bf(tile[kl*65 + nl]);
  }
}

__global__ void wtrans_kernel(const float* __restrict__ W, short* __restrict__ dst,
                              int Kd, int Nd){
  __shared__ __align__(16) float tile[64*65];
  int n0 = blockIdx.x*64, k0 = blockIdx.y*64;
  #pragma unroll
  for (int i = 0; i < 16; ++i){
    int e = threadIdx.x + 256*i; int kl = e >> 6, nl = e & 63;
    tile[kl*65 + nl] = W[(size_t)(k0 + kl)*Nd + n0 + nl];
  }
  __syncthreads();
  #pragma unroll
  for (int i = 0; i < 16; ++i){
    int e = threadIdx.x + 256*i; int nl = e >> 6, kl = e & 63;
    dst[(size_t)(n0 + nl)*Kd + k0 + kl] = f2bf(tile[kl*65 + nl]);
  }
}

// interleaved w1/w3 (z=0 -> w1/off0, z=1 -> w3/off16)
__global__ void wtrans_inter2_kernel(const float* __restrict__ w1p, const float* __restrict__ w3p,
                                     short* __restrict__ dst){
  __shared__ __align__(16) float tile[64*65];
  const float* W = blockIdx.z ? w3p : w1p;
  const int off16 = blockIdx.z ? 16 : 0;
  int n0 = blockIdx.x*64, k0 = blockIdx.y*64;
  #pragma unroll
  for (int i = 0; i < 16; ++i){
    int e = threadIdx.x + 256*i; int kl = e >> 6, nl = e & 63;
    tile[kl*65 + nl] = W[(size_t)(k0 + kl)*4096 + n0 + nl];
  }
  __syncthreads();
  #pragma unroll
  for (int i = 0; i < 16; ++i){
    int e = threadIdx.x + 256*i; int nl = e >> 6, kl = e & 63;
    int c = n0 + nl;
    int frow = ((c >> 4) << 5) + off16 + (c & 15);
    dst[(size_t)frow*1024 + k0 + kl] = f2bf(tile[kl*65 + nl]);
  }
}

// ---------------- fused x += sum(psum[0..NS-1]) (bf16 partials) then RMSNorm ---
template<int OUT_BF16, int NS>
__global__ void redrms_kernel(float* __restrict__ x, const short* __restrict__ Cp,
                              const float* __restrict__ w, void* __restrict__ outv){
  int row = blockIdx.x, tid = threadIdx.x;
  size_t i = (size_t)row*256 + tid;
  float4 a = ((float4*)x)[i];
  #pragma unroll
  for (int s = 0; s < NS; ++s){
    short4 q = ((const short4*)Cp)[(size_t)s*1048576 + i];
    a.x += bf2f(q.x); a.y += bf2f(q.y); a.z += bf2f(q.z); a.w += bf2f(q.w);
  }
  if (OUT_BF16) ((float4*)x)[i] = a;
  float ss = a.x*a.x + a.y*a.y + a.z*a.z + a.w*a.w;
  #pragma unroll
  for (int m = 1; m < 64; m <<= 1) ss += __shfl_xor(ss, m);
  __shared__ float red[4];
  if ((tid & 63) == 0) red[tid >> 6] = ss;
  __syncthreads();
  float tot = red[0] + red[1] + red[2] + red[3];
  float scale = rsqrtf(tot * (1.0f/1024.0f) + 1e-5f);
  const float4 wv = ((const float4*)w)[tid];
  if (OUT_BF16){
    short4 o;
    o.x = f2bf(a.x*scale*wv.x); o.y = f2bf(a.y*scale*wv.y);
    o.z = f2bf(a.z*scale*wv.z); o.w = f2bf(a.w*scale*wv.w);
    ((short4*)outv)[(size_t)row*256 + tid] = o;
  } else {
    float4 o;
    o.x = a.x*scale*wv.x; o.y = a.y*scale*wv.y;
    o.z = a.z*scale*wv.z; o.w = a.w*scale*wv.w;
    ((float4*)outv)[(size_t)row*256 + tid] = o;
  }
}

// ---------------- block-index swizzle (m204 bijective XCD + GM raster) ----------
__device__ __forceinline__ void swz_block_id(int id, int NX, int NY, int& bm, int& bn){
  const int nwg = NX*NY;
  const int qq = nwg >> 3, rr8 = nwg & 7;
  const int xcd = id & 7, loc = id >> 3;
  const int wgid = (xcd < rr8 ? xcd*(qq+1) : rr8*(qq+1) + (xcd-rr8)*qq) + loc;
  const int GM = 8;
  const int gsz = GM * NX;
  const int gidg = wgid / gsz;
  const int remg = wgid - gidg*gsz;
  bm = gidg*GM + (remg % GM);
  bn = remg / GM;
}

// ---------------- GEMM split-K 2-phase 128x128 -> bf16 partials (WO) -----------
__global__ __launch_bounds__(256) void gemm_splitk(const short* __restrict__ A,
                                                   const short* __restrict__ Bt,
                                                   short* __restrict__ Cp,
                                                   int M, int N, int Ktot, int Kchunk,
                                                   int NX, int NY){
  __shared__ __align__(16) short sA[2][128*32];
  __shared__ __align__(16) short sB[2][128*32];
  const int tid = threadIdx.x;
  const int lane = tid & 63, wid = tid >> 6;
  const int wm = wid >> 1, wn = wid & 1;
  const int lr = lane & 15, lg = lane >> 4;
  const int nin = NX*NY;
  const int split = blockIdx.x / nin;
  const int inner = blockIdx.x - split*nin;
  int bm, bn; swz_block_id(inner, NX, NY, bm, bn);
  const int bm0 = bm * 128, bn0 = bn * 128;
  const int koff = split * Kchunk;

  f32x4 acc[4][4];
  #pragma unroll
  for (int i = 0; i < 4; ++i)
    #pragma unroll
    for (int j = 0; j < 4; ++j) acc[i][j] = (f32x4){0.f,0.f,0.f,0.f};

  const short* gA = A  + (size_t)(bm0 + wid*32 + (lane >> 2))*Ktot + koff + (lane & 3)*8;
  const short* gB = Bt + (size_t)(bn0 + wid*32 + (lane >> 2))*Ktot + koff + (lane & 3)*8;

  #pragma unroll
  for (int iss = 0; iss < 2; ++iss){
    GLOAD16(gA + (size_t)iss*16*Ktot, &sA[0][wid*1024 + iss*16*32]);
    GLOAD16(gB + (size_t)iss*16*Ktot, &sB[0][wid*1024 + iss*16*32]);
  }
  __syncthreads();

  int cur = 0;
  for (int k0 = 0; k0 < Kchunk; k0 += 32){
    if (k0 + 32 < Kchunk){
      #pragma unroll
      for (int iss = 0; iss < 2; ++iss){
        GLOAD16(gA + (size_t)iss*16*Ktot + k0 + 32, &sA[cur^1][wid*1024 + iss*16*32]);
        GLOAD16(gB + (size_t)iss*16*Ktot + k0 + 32, &sB[cur^1][wid*1024 + iss*16*32]);
      }
    }
    s16x8 af[4], bq[4];
    #pragma unroll
    for (int i = 0; i < 4; ++i) af[i] = *(const s16x8*)&sA[cur][(wm*64 + i*16 + lr)*32 + lg*8];
    #pragma unroll
    for (int j = 0; j < 4; ++j) bq[j] = *(const s16x8*)&sB[cur][(wn*64 + j*16 + lr)*32 + lg*8];
    #pragma unroll
    for (int i = 0; i < 4; ++i)
      #pragma unroll
      for (int j = 0; j < 4; ++j)
        acc[i][j] = __builtin_amdgcn_mfma_f32_16x16x32_bf16(af[i], bq[j], acc[i][j], 0, 0, 0);
    __syncthreads();
    cur ^= 1;
  }

  short* C = Cp + (size_t)split*M*N;
  #pragma unroll
  for (int i = 0; i < 4; ++i){
    int row0 = bm0 + wm*64 + i*16 + lg*4;
    #pragma unroll
    for (int j = 0; j < 4; ++j){
      int col = bn0 + wn*64 + j*16 + lr;
      #pragma unroll
      for (int r = 0; r < 4; ++r) C[(size_t)(row0 + r)*N + col] = f2bf(acc[i][j][r]);
    }
  }
}

// ---------------- GEMM 4-phase 256x256, BK=64, SINGLE-buffer unit recycling ----
// LDS: 4 units (u0=A-ks0,u1=B-ks0,u2=A-ks1,u3=B-ks1) x [256][32] bf16 = 64 KiB
// -> 2 blocks/CU (16 waves) so inter-block TLP hides barrier/vmcnt drains.
// Unit uX of tile kt is dead after its last reader phase; kt(+1) units stage
// into freed slots: kt.u3@ph0, kt+1.u0@ph1, kt+1.u1@ph2, kt+1.u2@ph3.
// vmcnt(2) at ends of ph1 (retires kt.u2,kt.u3) and ph3 (retires kt+1.u0,u1).
#define STAGE8(u, kt) do { \
  const short* Gp_ = ((u)&1) ? Bt : A; \
  const int rb_ = ((u)&1) ? bn0 : bm0; \
  const int kh_ = (u)>>1; \
  _Pragma("unroll") \
  for (int L_ = 0; L_ < 2; ++L_){ \
    int rowS_ = L_*128 + wid*16 + (lane>>2); \
    int sp_ = (lane&3) ^ ((rowS_>>1)&3); \
    GLOAD16(Gp_ + (size_t)(rb_ + rowS_)*Kstr + (size_t)(kt)*64 + kh_*32 + sp_*8, \
            &sAB[u][(L_*512 + wid*64)*8]); \
  } \
} while(0)

#define LDSRD(u, rowv) \
  (*(const s16x8*)&sAB[u][(rowv)*32 + (((lg) ^ (((rowv)>>1)&3))<<3)])

// FUSE 0: bf16 C[M,N].  FUSE 1: silu-fused interleaved -> bf16 C[M,N/2].
// FUSE 2: bf16 partial at Cp + split*M*N (split-K).
// FUSE 3: fused QKV epilogue: q->RoPE+scale->Qo, k->RoPE->Ko, v->transposed Vo.
template<int FUSE>
__global__ __launch_bounds__(512, 4) void gemm8p(const short* __restrict__ A,
                                                 const short* __restrict__ Bt,
                                                 void* __restrict__ Cv,
                                                 short* __restrict__ Qo,
                                                 short* __restrict__ Ko,
                                                 short* __restrict__ Vo,
                                                 const float* __restrict__ cosb,
                                                 const float* __restrict__ sinb,
                                                 int M, int N, int Kstr, int Kchunk,
                                                 int NX, int NY){
  __shared__ __align__(16) short sAB[4][256*32];
  const int tid = threadIdx.x;
  const int lane = tid & 63, wid = tid >> 6;
  const int wm = wid >> 2, wn = wid & 3;
  const int lr = lane & 15, lg = lane >> 4;
  const int nin = NX*NY;
  const int split = blockIdx.x / nin;
  const int inner = blockIdx.x - split*nin;
  int bm, bn; swz_block_id(inner, NX, NY, bm, bn);
  const int bm0 = bm * 256, bn0 = bn * 256;
  A  += (size_t)split * Kchunk;
  Bt += (size_t)split * Kchunk;

  f32x4 acc[8][4];
  #pragma unroll
  for (int i = 0; i < 8; ++i)
    #pragma unroll
    for (int j = 0; j < 4; ++j) acc[i][j] = (f32x4){0.f,0.f,0.f,0.f};

  const int NK = Kchunk >> 6;
  // prologue: stage t0.u0,u1,u2 (6 loads); u3 staged at ph0.
  STAGE8(0, 0); STAGE8(1, 0); STAGE8(2, 0);
  asm volatile("s_waitcnt vmcnt(2)" ::: "memory");   // u0,u1 ready; u2 in flight
  __builtin_amdgcn_s_barrier();

  s16x8 afp[8];
  #pragma unroll 1
  for (int kt = 0; kt < NK; ++kt){
    const bool st1 = (kt + 1 < NK);

    // ---- ph0: reads u0 (A x8), u1 (B c0,c1); stage kt.u3 ----
    STAGE8(3, kt);
    {
      #pragma unroll
      for (int i_ = 0; i_ < 8; ++i_) afp[i_] = LDSRD(0, wm*128 + i_*16 + lr);
      s16x8 b0 = LDSRD(1, wn*64 + lr);
      s16x8 b1 = LDSRD(1, wn*64 + 16 + lr);
      __builtin_amdgcn_s_barrier();
      asm volatile("s_waitcnt lgkmcnt(0)" ::: "memory");
      __builtin_amdgcn_s_setprio(1);
      #pragma unroll
      for (int i_ = 0; i_ < 8; ++i_){
        acc[i_][0] = __builtin_amdgcn_mfma_f32_16x16x32_bf16(afp[i_], b0, acc[i_][0], 0, 0, 0);
        acc[i_][1] = __builtin_amdgcn_mfma_f32_16x16x32_bf16(afp[i_], b1, acc[i_][1], 0, 0, 0);
      }
      __builtin_amdgcn_s_setprio(0);
      __builtin_amdgcn_s_barrier();
    }
    // ---- ph1: reads u1 (B c2,c3); stage kt+1.u0 ----
    if (st1) STAGE8(0, kt+1);
    {
      s16x8 b2 = LDSRD(1, wn*64 + 32 + lr);
      s16x8 b3 = LDSRD(1, wn*64 + 48 + lr);
      __builtin_amdgcn_s_barrier();
      asm volatile("s_waitcnt lgkmcnt(0)" ::: "memory");
      __builtin_amdgcn_s_setprio(1);
      #pragma unroll
      for (int i_ = 0; i_ < 8; ++i_){
        acc[i_][2] = __builtin_amdgcn_mfma_f32_16x16x32_bf16(afp[i_], b2, acc[i_][2], 0, 0, 0);
        acc[i_][3] = __builtin_amdgcn_mfma_f32_16x16x32_bf16(afp[i_], b3, acc[i_][3], 0, 0, 0);
      }
      __builtin_amdgcn_s_setprio(0);
      if (st1) asm volatile("s_waitcnt vmcnt(2)" ::: "memory");  // retire kt.u2, kt.u3
      else     asm volatile("s_waitcnt vmcnt(0)" ::: "memory");
      __builtin_amdgcn_s_barrier();
    }
    // ---- ph2: reads u2 (A x8), u3 (B c0,c1); stage kt+1.u1 ----
    if (st1) STAGE8(1, kt+1);
    {
      #pragma unroll
      for (int i_ = 0; i_ < 8; ++i_) afp[i_] = LDSRD(2, wm*128 + i_*16 + lr);
      s16x8 b0 = LDSRD(3, wn*64 + lr);
      s16x8 b1 = LDSRD(3, wn*64 + 16 + lr);
      __builtin_amdgcn_s_barrier();
      asm volatile("s_waitcnt lgkmcnt(0)" ::: "memory");
      __builtin_amdgcn_s_setprio(1);
      #pragma unroll
      for (int i_ = 0; i_ < 8; ++i_){
        acc[i_][0] = __builtin_amdgcn_mfma_f32_16x16x32_bf16(afp[i_], b0, acc[i_][0], 0, 0, 0);
        acc[i_][1] = __builtin_amdgcn_mfma_f32_16x16x32_bf16(afp[i_], b1, acc[i_][1], 0, 0, 0);
      }
      __builtin_amdgcn_s_setprio(0);
      __builtin_amdgcn_s_barrier();
    }
    // ---- ph3: reads u3 (B c2,c3); stage kt+1.u2 ----
    if (st1) STAGE8(2, kt+1);
    {
      s16x8 b2 = LDSRD(3, wn*64 + 32 + lr);
      s16x8 b3 = LDSRD(3, wn*64 + 48 + lr);
      __builtin_amdgcn_s_barrier();
      asm volatile("s_waitcnt lgkmcnt(0)" ::: "memory");
      __builtin_amdgcn_s_setprio(1);
      #pragma unroll
      for (int i_ = 0; i_ < 8; ++i_){
        acc[i_][2] = __builtin_amdgcn_mfma_f32_16x16x32_bf16(afp[i_], b2, acc[i_][2], 0, 0, 0);
        acc[i_][3] = __builtin_amdgcn_mfma_f32_16x16x32_bf16(afp[i_], b3, acc[i_][3], 0, 0, 0);
      }
      __builtin_amdgcn_s_setprio(0);
      if (st1) asm volatile("s_waitcnt vmcnt(2)" ::: "memory");  // retire kt+1.u0,u1
      __builtin_amdgcn_s_barrier();
    }
  }

  if (FUSE == 0){
    short* C = (short*)Cv;
    #pragma unroll
    for (int i = 0; i < 8; ++i){
      int row0 = bm0 + wm*128 + i*16 + lg*4;
      #pragma unroll
      for (int j = 0; j < 4; ++j){
        int col = bn0 + wn*64 + j*16 + lr;
        #pragma unroll
        for (int r = 0; r < 4; ++r) C[(size_t)(row0 + r)*N + col] = f2bf(acc[i][j][r]);
      }
    }
  } else if (FUSE == 1){
    short* C = (short*)Cv;
    const int Nh = N >> 1;
    #pragma unroll
    for (int i = 0; i < 8; ++i){
      int row0 = bm0 + wm*128 + i*16 + lg*4;
      #pragma unroll
      for (int jp = 0; jp < 2; ++jp){
        int col = (bn0 >> 1) + wn*32 + jp*16 + lr;
        #pragma unroll
        for (int r = 0; r < 4; ++r){
          float u = acc[i][jp*2][r], g = acc[i][jp*2+1][r];
          float val = u / (1.f + __expf(-u)) * g;
          C[(size_t)(row0 + r)*Nh + col] = f2bf(val);
        }
      }
    }
  } else if (FUSE == 2){
    short* C = (short*)Cv + (size_t)split*M*N;
    #pragma unroll
    for (int i = 0; i < 8; ++i){
      int row0 = bm0 + wm*128 + i*16 + lg*4;
      #pragma unroll
      for (int j = 0; j < 4; ++j){
        int col = bn0 + wn*64 + j*16 + lr;
        #pragma unroll
        for (int r = 0; r < 4; ++r) C[(size_t)(row0 + r)*N + col] = f2bf(acc[i][j][r]);
      }
    }
  } else {
    const int part = bn0 >> 10;
    const int colb = bn0 & 1023;
    const int h = (colb + wn*64) >> 6;
    if (part < 2){
      short* dst = (part == 0) ? Qo : Ko;
      const float qs = (part == 0) ? 0.1803368801111204f : 1.0f; // 0.125*log2(e)
      #pragma unroll
      for (int i = 0; i < 8; ++i){
        int row0 = bm0 + wm*128 + i*16 + lg*4;
        #pragma unroll
        for (int jh = 0; jh < 2; ++jh){
          int d = jh*16 + lr;
          #pragma unroll
          for (int r = 0; r < 4; ++r){
            int tg = row0 + r;
            int bb = tg >> 11, tt = tg & 2047;
            float c = cosb[tt*64 + d], s = sinb[tt*64 + d];
            float x0 = acc[i][jh][r], x1 = acc[i][jh+2][r];
            float y0 = (x0*c - x1*s)*qs;
            float y1 = (x1*c + x0*s)*qs;
            size_t o = ((size_t)(bb*CT + tt)*CNH + h)*CHD;
            dst[o + d]      = f2bf(y0);
            dst[o + d + 32] = f2bf(y1);
          }
        }
      }
    } else {
      #pragma unroll
      for (int i = 0; i < 8; ++i){
        int row0 = bm0 + wm*128 + i*16 + lg*4;
        int bb = row0 >> 11, t0 = row0 & 2047;
        #pragma unroll
        for (int j = 0; j < 4; ++j){
          int d = j*16 + lr;
          short4 pk;
          pk.x = f2bf(acc[i][j][0]); pk.y = f2bf(acc[i][j][1]);
          pk.z = f2bf(acc[i][j][2]); pk.w = f2bf(acc[i][j][3]);
          *(short4*)&Vo[((size_t)(bb*CNH + h)*CHD + d)*CT + t0] = pk;
        }
      }
    }
  }
}

// ---------------- causal flash attention v3 (round-13 proven) ----------------
__global__ __launch_bounds__(256) void attn_kernel(const short* __restrict__ Q,
                                                   const short* __restrict__ Kb,
                                                   const short* __restrict__ Vt,
                                                   short* __restrict__ O){
  __shared__ __align__(16) short Kl[2][64*72];
  __shared__ __align__(16) short Vl[2][64*72];
  __shared__ __align__(16) short Pl[4][16*72];
  const int tid = threadIdx.x, lane = tid & 63, w = tid >> 6;
  const int qpair = blockIdx.x;          // 0..15
  const int h = blockIdx.y, b = blockIdx.z;
  const int lr = lane & 15, lg = lane >> 4;

  const short* gK = Kb + (size_t)b*CT*CD + h*CHD;
  const short* gV = Vt + (size_t)(b*CNH + h)*CHD*CT;
  const int srow0 = tid >> 3, scol = (tid & 7)*8;

  #pragma unroll 1
  for (int half = 0; half < 2; ++half){
    const int qt = half ? qpair : (31 - qpair);
    const int wq0 = qt*64 + w*16;
    const int jmax = qt + 1;

    s16x8 qf0, qf1;
    {
      const short* qp = Q + ((size_t)(b*CT + wq0 + lr)*CNH + h)*CHD + lg*8;
      qf0 = *(const s16x8*)qp;
      qf1 = *(const s16x8*)(qp + 32);
    }
    f32x4 oacc[4];
    #pragma unroll
    for (int dt = 0; dt < 4; ++dt) oacc[dt] = (f32x4){0.f,0.f,0.f,0.f};
    float m_r = -1e30f, l_r = 0.f;

    #pragma unroll
    for (int p = 0; p < 2; ++p){
      int row = srow0 + p*32;
      *(s16x8*)&Kl[0][row*72 + scol] = *(const s16x8*)(gK + (size_t)row*CD + scol);
      *(s16x8*)&Vl[0][row*72 + scol] = *(const s16x8*)(gV + (size_t)row*CT + scol);
    }
    __syncthreads();

    #pragma unroll 1
    for (int j = 0; j < jmax; ++j){
      const int kv0 = j*64;
      const int buf = j & 1;
      s16x8 nk[2], nv[2];
      const bool havenext = (j + 1 < jmax);
      if (havenext){
        const int kv1 = kv0 + 64;
        #pragma unroll
        for (int p = 0; p < 2; ++p){
          int row = srow0 + p*32;
          nk[p] = *(const s16x8*)(gK + (size_t)(kv1 + row)*CD + scol);
          nv[p] = *(const s16x8*)(gV + (size_t)row*CT + kv1 + scol);
        }
      }

      if (kv0 < wq0 + 16){
        f32x4 sc[4];
        __builtin_amdgcn_s_setprio(1);
        #pragma unroll
        for (int nt = 0; nt < 4; ++nt){
          s16x8 k0 = *(const s16x8*)&Kl[buf][(nt*16 + lr)*72 + lg*8];
          s16x8 k1 = *(const s16x8*)&Kl[buf][(nt*16 + lr)*72 + 32 + lg*8];
          f32x4 z = (f32x4){0.f,0.f,0.f,0.f};
          z = __builtin_amdgcn_mfma_f32_16x16x32_bf16(k0, qf0, z, 0, 0, 0);
          z = __builtin_amdgcn_mfma_f32_16x16x32_bf16(k1, qf1, z, 0, 0, 0);
          sc[nt] = z;
        }
        __builtin_amdgcn_s_setprio(0);
        if (kv0 + 64 > wq0){
          #pragma unroll
          for (int nt = 0; nt < 4; ++nt)
            #pragma unroll
            for (int r = 0; r < 4; ++r)
              if (kv0 + nt*16 + lg*4 + r > wq0 + lr) sc[nt][r] = -1e30f;
        }
        float pmax = sc[0][0];
        #pragma unroll
        for (int nt = 0; nt < 4; ++nt)
          #pragma unroll
          for (int r = 0; r < 4; ++r) pmax = fmaxf(pmax, sc[nt][r]);
        pmax = fmaxf(pmax, __shfl_xor(pmax, 16));
        pmax = fmaxf(pmax, __shfl_xor(pmax, 32));
        if (!__all(pmax - m_r <= 10.f)){
          float mn = fmaxf(m_r, pmax);
          float corr = __builtin_amdgcn_exp2f(m_r - mn);
          m_r = mn;
          l_r *= corr;
          #pragma unroll
          for (int r = 0; r < 4; ++r){
            float c4 = __shfl(corr, lg*4 + r);
            #pragma unroll
            for (int dt = 0; dt < 4; ++dt) oacc[dt][r] *= c4;
          }
        }
        float rs = 0.f;
        #pragma unroll
        for (int nt = 0; nt < 4; ++nt)
          #pragma unroll
          for (int r = 0; r < 4; ++r){
            float pv = __builtin_amdgcn_exp2f(sc[nt][r] - m_r);
            sc[nt][r] = pv;
            rs += pv;
          }
        #pragma unroll
        for (int nt = 0; nt < 4; ++nt){
          uint2 pk;
          pk.x = cvtpk_bf16(sc[nt][0], sc[nt][1]);
          pk.y = cvtpk_bf16(sc[nt][2], sc[nt][3]);
          *(uint2*)&Pl[w][lr*72 + nt*16 + lg*4] = pk;
        }
        rs += __shfl_xor(rs, 16);
        rs += __shfl_xor(rs, 32);
        l_r += rs;
        s16x8 pa0 = *(const s16x8*)&Pl[w][lr*72 + lg*8];
        s16x8 pa1 = *(const s16x8*)&Pl[w][lr*72 + 32 + lg*8];
        __builtin_amdgcn_s_setprio(1);
        #pragma unroll
        for (int dt = 0; dt < 4; ++dt){
          s16x8 v0 = *(const s16x8*)&Vl[buf][(dt*16 + lr)*72 + lg*8];
          s16x8 v1 = *(const s16x8*)&Vl[buf][(dt*16 + lr)*72 + 32 + lg*8];
          oacc[dt] = __builtin_amdgcn_mfma_f32_16x16x32_bf16(pa0, v0, oacc[dt], 0, 0, 0);
          oacc[dt] = __builtin_amdgcn_mfma_f32_16x16x32_bf16(pa1, v1, oacc[dt], 0, 0, 0);
        }
        __builtin_amdgcn_s_setprio(0);
      }
      if (havenext){
        #pragma unroll
        for (int p = 0; p < 2; ++p){
          int row = srow0 + p*32;
          *(s16x8*)&Kl[buf^1][row*72 + scol] = nk[p];
          *(s16x8*)&Vl[buf^1][row*72 + scol] = nv[p];
        }
      }
      __syncthreads();
    }

    #pragma unroll
    for (int r = 0; r < 4; ++r){
      float lf = __shfl(l_r, lg*4 + r);
      float inv = 1.f / lf;
      int qrow = wq0 + lg*4 + r;
      #pragma unroll
      for (int dt = 0; dt < 4; ++dt)
        O[((size_t)(b*CT + qrow)*CNH + h)*CHD + dt*16 + lr] = f2bf(oacc[dt][r] * inv);
    }
  }
}

// ---------------- launch ----------------
extern "C" void kernel_launch(void* const* d_in, const int* in_sizes, int n_in,
                              void* d_out, int out_size, void* d_ws, size_t ws_size,
                              hipStream_t stream){
  (void)in_sizes; (void)n_in; (void)out_size; (void)ws_size;
  const float* x_processed = (const float*)d_in[0];
  const int*   boundaries  = (const int*)d_in[1];
  const float* x_residual  = (const float*)d_in[3];
  const float* cosb        = (const float*)d_in[4];
  const float* sinb        = (const float*)d_in[5];
  const float* wq          = (const float*)d_in[7];
  const float* wk          = (const float*)d_in[8];
  const float* wv          = (const float*)d_in[9];
  const float* wo          = (const float*)d_in[10];
  const float* attn_nw     = (const float*)d_in[11];
  const float* mlp_nw      = (const float*)d_in[12];
  const float* w1          = (const float*)d_in[13];
  const float* w3          = (const float*)d_in[14];
  const float* w2          = (const float*)d_in[15];
  const float* final_nw    = (const float*)d_in[16];

  char* p = (char*)d_ws;
  auto alloc = [&](size_t bytes)->char*{
    char* r = p; p += (bytes + 255) & ~(size_t)255; return r;
  };
  short* wqkvT = (short*)alloc((size_t)2*3072*1024*2);
  short* woT   = (short*)alloc((size_t)2*1024*1024*2);
  short* w13T  = (short*)alloc((size_t)2*8192*1024*2);
  short* w2T   = (short*)alloc((size_t)2*1024*4096*2);
  float* x     = (float*)alloc((size_t)4096*1024*4);
  short* hbuf  = (short*)alloc((size_t)4096*1024*2);
  short* qr    = (short*)alloc((size_t)4096*1024*2);
  short* kr    = (short*)alloc((size_t)4096*1024*2);
  short* vt    = (short*)alloc((size_t)4096*1024*2);
  short* obuf  = (short*)alloc((size_t)4096*1024*2);
  short* mbuf  = (short*)alloc((size_t)4096*4096*2);
  short* psum  = (short*)alloc((size_t)4*4096*1024*2);

  for (int l = 0; l < 2; ++l){
    size_t wOff = (size_t)l*1024*1024;
    wtrans_qkvo_kernel<<<dim3(16,16,4),256,0,stream>>>(wq + wOff, wk + wOff, wv + wOff, wo + wOff,
                                                       wqkvT + (size_t)l*3072*1024, woT + (size_t)l*1024*1024);
    wtrans_inter2_kernel<<<dim3(64,16,2),256,0,stream>>>(w1 + (size_t)l*1024*4096, w3 + (size_t)l*1024*4096,
                                                         w13T + (size_t)l*8192*1024);
    wtrans_kernel<<<dim3(16,64),256,0,stream>>>(w2 + (size_t)l*4096*1024, w2T + (size_t)l*1024*4096, 4096, 1024);
  }
  gather_rms_kernel<<<4096,256,0,stream>>>(x_processed, boundaries, x_residual, attn_nw, x, hbuf);
  for (int l = 0; l < 2; ++l){
    gemm8p<3><<<12*16,512,0,stream>>>(hbuf, wqkvT + (size_t)l*3072*1024, nullptr,
                                      qr, kr, vt, cosb, sinb,
                                      4096, 3072, 1024, 1024, 12, 16);
    attn_kernel<<<dim3(16,16,2),256,0,stream>>>(qr, kr, vt, obuf);
    gemm_splitk<<<8*32*4,256,0,stream>>>(obuf, woT + (size_t)l*1024*1024, psum,
                                         4096, 1024, 1024, 256, 8, 32);
    redrms_kernel<1,4><<<4096,256,0,stream>>>(x, psum, mlp_nw + l*1024, hbuf);
    gemm8p<1><<<32*16,512,0,stream>>>(hbuf, w13T + (size_t)l*8192*1024, mbuf,
                                      nullptr, nullptr, nullptr, nullptr, nullptr,
                                      4096, 8192, 1024, 1024, 32, 16);
    gemm8p<2><<<4*4*16,512,0,stream>>>(mbuf, w2T + (size_t)l*1024*4096, psum,
                                       nullptr, nullptr, nullptr, nullptr, nullptr,
                                       4096, 1024, 4096, 1024, 4, 16);
    if (l == 0) redrms_kernel<1,4><<<4096,256,0,stream>>>(x, psum, attn_nw + 1024, hbuf);
    else        redrms_kernel<0,4><<<4096,256,0,stream>>>(x, psum, final_nw, d_out);
  }
}

// Round 17
// 543.253 us; speedup vs baseline: 6.0777x; 6.0777x over previous
//
#include <hip/hip_runtime.h>
#include <stdint.h>

typedef __attribute__((ext_vector_type(8))) short s16x8;
typedef __attribute__((ext_vector_type(4))) float f32x4;

#define CB 2
#define CT 2048
#define CD 1024
#define CNH 16
#define CHD 64
#define CDFF 4096
#define CKB 512

__device__ __forceinline__ short f2bf(float f){
  union { float f; uint32_t u; } v; v.f = f;
  uint32_t r = v.u + 0x7FFFu + ((v.u >> 16) & 1u);
  return (short)(r >> 16);
}
__device__ __forceinline__ float bf2f(short h){
  union { uint32_t u; float f; } v; v.u = ((uint32_t)(uint16_t)h) << 16;
  return v.f;
}
__device__ __forceinline__ uint32_t cvtpk_bf16(float lo, float hi){
  uint32_t r;
  asm("v_cvt_pk_bf16_f32 %0, %1, %2" : "=v"(r) : "v"(lo), "v"(hi));
  return r;
}

#define GLOAD16(g, l) __builtin_amdgcn_global_load_lds( \
    (const __attribute__((address_space(1))) void*)(g), \
    (__attribute__((address_space(3))) void*)(l), 16, 0, 0)

// ---------------- fused gather + residual + RMSNorm ----------------
__global__ void gather_rms_kernel(const float* __restrict__ xp, const int* __restrict__ bnd,
                                  const float* __restrict__ xr, const float* __restrict__ w,
                                  float* __restrict__ x, short* __restrict__ hbuf){
  int row = blockIdx.x;                  // b*2048 + t
  int b = row >> 11, t = row & 2047;
  int tid = threadIdx.x;
  int lo = 0, hi = CKB;
  while (lo < hi){ int mid = (lo + hi) >> 1; if (bnd[b*CKB + mid] <= t) lo = mid + 1; else hi = mid; }
  const float4 s  = ((const float4*)(xp + ((size_t)b*CKB + lo)*CD))[tid];
  const float4 rr = ((const float4*)(xr + (size_t)row*CD))[tid];
  float4 a; a.x = s.x + rr.x; a.y = s.y + rr.y; a.z = s.z + rr.z; a.w = s.w + rr.w;
  ((float4*)(x + (size_t)row*CD))[tid] = a;
  float ss = a.x*a.x + a.y*a.y + a.z*a.z + a.w*a.w;
  #pragma unroll
  for (int m = 1; m < 64; m <<= 1) ss += __shfl_xor(ss, m);
  __shared__ float red[4];
  if ((tid & 63) == 0) red[tid >> 6] = ss;
  __syncthreads();
  float tot = red[0] + red[1] + red[2] + red[3];
  float scale = rsqrtf(tot * (1.0f/1024.0f) + 1e-5f);
  const float4 wv = ((const float4*)w)[tid];
  short4 o;
  o.x = f2bf(a.x*scale*wv.x); o.y = f2bf(a.y*scale*wv.y);
  o.z = f2bf(a.z*scale*wv.z); o.w = f2bf(a.w*scale*wv.w);
  ((short4*)hbuf)[(size_t)row*256 + tid] = o;
}

// ---------------- weight fp32 -> bf16 transposes (merged) ----------------
__global__ void wtrans_qkvo_kernel(const float* __restrict__ wq, const float* __restrict__ wk,
                                   const float* __restrict__ wv, const float* __restrict__ wo,
                                   short* __restrict__ qkvT, short* __restrict__ woT){
  __shared__ __align__(16) float tile[64*65];
  const float* W; short* dst;
  const int z = blockIdx.z;
  if (z == 0){ W = wq; dst = qkvT; }
  else if (z == 1){ W = wk; dst = qkvT + (size_t)1024*1024; }
  else if (z == 2){ W = wv; dst = qkvT + (size_t)2048*1024; }
  else { W = wo; dst = woT; }
  int n0 = blockIdx.x*64, k0 = blockIdx.y*64;
  #pragma unroll
  for (int i = 0; i < 16; ++i){
    int e = threadIdx.x + 256*i; int kl = e >> 6, nl = e & 63;
    tile[kl*65 + nl] = W[(size_t)(k0 + kl)*1024 + n0 + nl];
  }
  __syncthreads();
  #pragma unroll
  for (int i = 0; i < 16; ++i){
    int e = threadIdx.x + 256*i; int nl = e >> 6, kl = e & 63;
    dst[(size_t)(n0 + nl)*1024 + k0 + kl] = f2bf(tile[kl*65 + nl]);
  }
}

__global__ void wtrans_kernel(const float* __restrict__ W, short* __restrict__ dst,
                              int Kd, int Nd){
  __shared__ __align__(16) float tile[64*65];
  int n0 = blockIdx.x*64, k0 = blockIdx.y*64;
  #pragma unroll
  for (int i = 0; i < 16; ++i){
    int e = threadIdx.x + 256*i; int kl = e >> 6, nl = e & 63;
    tile[kl*65 + nl] = W[(size_t)(k0 + kl)*Nd + n0 + nl];
  }
  __syncthreads();
  #pragma unroll
  for (int i = 0; i < 16; ++i){
    int e = threadIdx.x + 256*i; int nl = e >> 6, kl = e & 63;
    dst[(size_t)(n0 + nl)*Kd + k0 + kl] = f2bf(tile[kl*65 + nl]);
  }
}

// interleaved w1/w3 (z=0 -> w1/off0, z=1 -> w3/off16)
__global__ void wtrans_inter2_kernel(const float* __restrict__ w1p, const float* __restrict__ w3p,
                                     short* __restrict__ dst){
  __shared__ __align__(16) float tile[64*65];
  const float* W = blockIdx.z ? w3p : w1p;
  const int off16 = blockIdx.z ? 16 : 0;
  int n0 = blockIdx.x*64, k0 = blockIdx.y*64;
  #pragma unroll
  for (int i = 0; i < 16; ++i){
    int e = threadIdx.x + 256*i; int kl = e >> 6, nl = e & 63;
    tile[kl*65 + nl] = W[(size_t)(k0 + kl)*4096 + n0 + nl];
  }
  __syncthreads();
  #pragma unroll
  for (int i = 0; i < 16; ++i){
    int e = threadIdx.x + 256*i; int nl = e >> 6, kl = e & 63;
    int c = n0 + nl;
    int frow = ((c >> 4) << 5) + off16 + (c & 15);
    dst[(size_t)frow*1024 + k0 + kl] = f2bf(tile[kl*65 + nl]);
  }
}

// ---------------- fused x += sum(psum[0..NS-1]) (bf16 partials) then RMSNorm ---
template<int OUT_BF16, int NS>
__global__ void redrms_kernel(float* __restrict__ x, const short* __restrict__ Cp,
                              const float* __restrict__ w, void* __restrict__ outv){
  int row = blockIdx.x, tid = threadIdx.x;
  size_t i = (size_t)row*256 + tid;
  float4 a = ((float4*)x)[i];
  #pragma unroll
  for (int s = 0; s < NS; ++s){
    short4 q = ((const short4*)Cp)[(size_t)s*1048576 + i];
    a.x += bf2f(q.x); a.y += bf2f(q.y); a.z += bf2f(q.z); a.w += bf2f(q.w);
  }
  if (OUT_BF16) ((float4*)x)[i] = a;
  float ss = a.x*a.x + a.y*a.y + a.z*a.z + a.w*a.w;
  #pragma unroll
  for (int m = 1; m < 64; m <<= 1) ss += __shfl_xor(ss, m);
  __shared__ float red[4];
  if ((tid & 63) == 0) red[tid >> 6] = ss;
  __syncthreads();
  float tot = red[0] + red[1] + red[2] + red[3];
  float scale = rsqrtf(tot * (1.0f/1024.0f) + 1e-5f);
  const float4 wv = ((const float4*)w)[tid];
  if (OUT_BF16){
    short4 o;
    o.x = f2bf(a.x*scale*wv.x); o.y = f2bf(a.y*scale*wv.y);
    o.z = f2bf(a.z*scale*wv.z); o.w = f2bf(a.w*scale*wv.w);
    ((short4*)outv)[(size_t)row*256 + tid] = o;
  } else {
    float4 o;
    o.x = a.x*scale*wv.x; o.y = a.y*scale*wv.y;
    o.z = a.z*scale*wv.z; o.w = a.w*scale*wv.w;
    ((float4*)outv)[(size_t)row*256 + tid] = o;
  }
}

// ---------------- block-index swizzle (m204 bijective XCD + GM raster) ----------
__device__ __forceinline__ void swz_block_id(int id, int NX, int NY, int& bm, int& bn){
  const int nwg = NX*NY;
  const int qq = nwg >> 3, rr8 = nwg & 7;
  const int xcd = id & 7, loc = id >> 3;
  const int wgid = (xcd < rr8 ? xcd*(qq+1) : rr8*(qq+1) + (xcd-rr8)*qq) + loc;
  const int GM = 8;
  const int gsz = GM * NX;
  const int gidg = wgid / gsz;
  const int remg = wgid - gidg*gsz;
  bm = gidg*GM + (remg % GM);
  bn = remg / GM;
}

// ---------------- GEMM split-K 2-phase 128x128 -> bf16 partials (WO) -----------
__global__ __launch_bounds__(256) void gemm_splitk(const short* __restrict__ A,
                                                   const short* __restrict__ Bt,
                                                   short* __restrict__ Cp,
                                                   int M, int N, int Ktot, int Kchunk,
                                                   int NX, int NY){
  __shared__ __align__(16) short sA[2][128*32];
  __shared__ __align__(16) short sB[2][128*32];
  const int tid = threadIdx.x;
  const int lane = tid & 63, wid = tid >> 6;
  const int wm = wid >> 1, wn = wid & 1;
  const int lr = lane & 15, lg = lane >> 4;
  const int nin = NX*NY;
  const int split = blockIdx.x / nin;
  const int inner = blockIdx.x - split*nin;
  int bm, bn; swz_block_id(inner, NX, NY, bm, bn);
  const int bm0 = bm * 128, bn0 = bn * 128;
  const int koff = split * Kchunk;

  f32x4 acc[4][4];
  #pragma unroll
  for (int i = 0; i < 4; ++i)
    #pragma unroll
    for (int j = 0; j < 4; ++j) acc[i][j] = (f32x4){0.f,0.f,0.f,0.f};

  const short* gA = A  + (size_t)(bm0 + wid*32 + (lane >> 2))*Ktot + koff + (lane & 3)*8;
  const short* gB = Bt + (size_t)(bn0 + wid*32 + (lane >> 2))*Ktot + koff + (lane & 3)*8;

  #pragma unroll
  for (int iss = 0; iss < 2; ++iss){
    GLOAD16(gA + (size_t)iss*16*Ktot, &sA[0][wid*1024 + iss*16*32]);
    GLOAD16(gB + (size_t)iss*16*Ktot, &sB[0][wid*1024 + iss*16*32]);
  }
  __syncthreads();

  int cur = 0;
  for (int k0 = 0; k0 < Kchunk; k0 += 32){
    if (k0 + 32 < Kchunk){
      #pragma unroll
      for (int iss = 0; iss < 2; ++iss){
        GLOAD16(gA + (size_t)iss*16*Ktot + k0 + 32, &sA[cur^1][wid*1024 + iss*16*32]);
        GLOAD16(gB + (size_t)iss*16*Ktot + k0 + 32, &sB[cur^1][wid*1024 + iss*16*32]);
      }
    }
    s16x8 af[4], bq[4];
    #pragma unroll
    for (int i = 0; i < 4; ++i) af[i] = *(const s16x8*)&sA[cur][(wm*64 + i*16 + lr)*32 + lg*8];
    #pragma unroll
    for (int j = 0; j < 4; ++j) bq[j] = *(const s16x8*)&sB[cur][(wn*64 + j*16 + lr)*32 + lg*8];
    #pragma unroll
    for (int i = 0; i < 4; ++i)
      #pragma unroll
      for (int j = 0; j < 4; ++j)
        acc[i][j] = __builtin_amdgcn_mfma_f32_16x16x32_bf16(af[i], bq[j], acc[i][j], 0, 0, 0);
    __syncthreads();
    cur ^= 1;
  }

  short* C = Cp + (size_t)split*M*N;
  #pragma unroll
  for (int i = 0; i < 4; ++i){
    int row0 = bm0 + wm*64 + i*16 + lg*4;
    #pragma unroll
    for (int j = 0; j < 4; ++j){
      int col = bn0 + wn*64 + j*16 + lr;
      #pragma unroll
      for (int r = 0; r < 4; ++r) C[(size_t)(row0 + r)*N + col] = f2bf(acc[i][j][r]);
    }
  }
}

// ---------------- GEMM 4-phase 256x256, BK=64, SINGLE-buffer unit recycling ----
// LDS: 4 units (u0=A-ks0,u1=B-ks0,u2=A-ks1,u3=B-ks1) x [256][32] bf16 = 64 KiB
// -> 2 blocks/CU (16 waves); natural VGPR (~100) <= 128 so no spill with
// __launch_bounds__(512,2). Unit recycling: kt.u3@ph0, kt+1.u0@ph1,
// kt+1.u1@ph2, kt+1.u2@ph3; vmcnt(2) at ph1/ph3 ends.
#define STAGE8(u, kt) do { \
  const short* Gp_ = ((u)&1) ? Bt : A; \
  const int rb_ = ((u)&1) ? bn0 : bm0; \
  const int kh_ = (u)>>1; \
  _Pragma("unroll") \
  for (int L_ = 0; L_ < 2; ++L_){ \
    int rowS_ = L_*128 + wid*16 + (lane>>2); \
    int sp_ = (lane&3) ^ ((rowS_>>1)&3); \
    GLOAD16(Gp_ + (size_t)(rb_ + rowS_)*Kstr + (size_t)(kt)*64 + kh_*32 + sp_*8, \
            &sAB[u][(L_*512 + wid*64)*8]); \
  } \
} while(0)

#define LDSRD(u, rowv) \
  (*(const s16x8*)&sAB[u][(rowv)*32 + (((lg) ^ (((rowv)>>1)&3))<<3)])

// FUSE 0: bf16 C[M,N].  FUSE 1: silu-fused interleaved -> bf16 C[M,N/2].
// FUSE 2: bf16 partial at Cp + split*M*N (split-K).
// FUSE 3: fused QKV epilogue: q->RoPE+scale->Qo, k->RoPE->Ko, v->transposed Vo.
template<int FUSE>
__global__ __launch_bounds__(512, 2) void gemm8p(const short* __restrict__ A,
                                                 const short* __restrict__ Bt,
                                                 void* __restrict__ Cv,
                                                 short* __restrict__ Qo,
                                                 short* __restrict__ Ko,
                                                 short* __restrict__ Vo,
                                                 const float* __restrict__ cosb,
                                                 const float* __restrict__ sinb,
                                                 int M, int N, int Kstr, int Kchunk,
                                                 int NX, int NY){
  __shared__ __align__(16) short sAB[4][256*32];
  const int tid = threadIdx.x;
  const int lane = tid & 63, wid = tid >> 6;
  const int wm = wid >> 2, wn = wid & 3;
  const int lr = lane & 15, lg = lane >> 4;
  const int nin = NX*NY;
  const int split = blockIdx.x / nin;
  const int inner = blockIdx.x - split*nin;
  int bm, bn; swz_block_id(inner, NX, NY, bm, bn);
  const int bm0 = bm * 256, bn0 = bn * 256;
  A  += (size_t)split * Kchunk;
  Bt += (size_t)split * Kchunk;

  f32x4 acc[8][4];
  #pragma unroll
  for (int i = 0; i < 8; ++i)
    #pragma unroll
    for (int j = 0; j < 4; ++j) acc[i][j] = (f32x4){0.f,0.f,0.f,0.f};

  const int NK = Kchunk >> 6;
  // prologue: stage t0.u0,u1,u2 (6 loads); u3 staged at ph0.
  STAGE8(0, 0); STAGE8(1, 0); STAGE8(2, 0);
  asm volatile("s_waitcnt vmcnt(2)" ::: "memory");   // u0,u1 ready; u2 in flight
  __builtin_amdgcn_s_barrier();

  s16x8 afp[8];
  #pragma unroll 1
  for (int kt = 0; kt < NK; ++kt){
    const bool st1 = (kt + 1 < NK);

    // ---- ph0: reads u0 (A x8), u1 (B c0,c1); stage kt.u3 ----
    STAGE8(3, kt);
    {
      #pragma unroll
      for (int i_ = 0; i_ < 8; ++i_) afp[i_] = LDSRD(0, wm*128 + i_*16 + lr);
      s16x8 b0 = LDSRD(1, wn*64 + lr);
      s16x8 b1 = LDSRD(1, wn*64 + 16 + lr);
      __builtin_amdgcn_s_barrier();
      asm volatile("s_waitcnt lgkmcnt(0)" ::: "memory");
      __builtin_amdgcn_s_setprio(1);
      #pragma unroll
      for (int i_ = 0; i_ < 8; ++i_){
        acc[i_][0] = __builtin_amdgcn_mfma_f32_16x16x32_bf16(afp[i_], b0, acc[i_][0], 0, 0, 0);
        acc[i_][1] = __builtin_amdgcn_mfma_f32_16x16x32_bf16(afp[i_], b1, acc[i_][1], 0, 0, 0);
      }
      __builtin_amdgcn_s_setprio(0);
      __builtin_amdgcn_s_barrier();
    }
    // ---- ph1: reads u1 (B c2,c3); stage kt+1.u0 ----
    if (st1) STAGE8(0, kt+1);
    {
      s16x8 b2 = LDSRD(1, wn*64 + 32 + lr);
      s16x8 b3 = LDSRD(1, wn*64 + 48 + lr);
      __builtin_amdgcn_s_barrier();
      asm volatile("s_waitcnt lgkmcnt(0)" ::: "memory");
      __builtin_amdgcn_s_setprio(1);
      #pragma unroll
      for (int i_ = 0; i_ < 8; ++i_){
        acc[i_][2] = __builtin_amdgcn_mfma_f32_16x16x32_bf16(afp[i_], b2, acc[i_][2], 0, 0, 0);
        acc[i_][3] = __builtin_amdgcn_mfma_f32_16x16x32_bf16(afp[i_], b3, acc[i_][3], 0, 0, 0);
      }
      __builtin_amdgcn_s_setprio(0);
      if (st1) asm volatile("s_waitcnt vmcnt(2)" ::: "memory");  // retire kt.u2, kt.u3
      else     asm volatile("s_waitcnt vmcnt(0)" ::: "memory");
      __builtin_amdgcn_s_barrier();
    }
    // ---- ph2: reads u2 (A x8), u3 (B c0,c1); stage kt+1.u1 ----
    if (st1) STAGE8(1, kt+1);
    {
      #pragma unroll
      for (int i_ = 0; i_ < 8; ++i_) afp[i_] = LDSRD(2, wm*128 + i_*16 + lr);
      s16x8 b0 = LDSRD(3, wn*64 + lr);
      s16x8 b1 = LDSRD(3, wn*64 + 16 + lr);
      __builtin_amdgcn_s_barrier();
      asm volatile("s_waitcnt lgkmcnt(0)" ::: "memory");
      __builtin_amdgcn_s_setprio(1);
      #pragma unroll
      for (int i_ = 0; i_ < 8; ++i_){
        acc[i_][0] = __builtin_amdgcn_mfma_f32_16x16x32_bf16(afp[i_], b0, acc[i_][0], 0, 0, 0);
        acc[i_][1] = __builtin_amdgcn_mfma_f32_16x16x32_bf16(afp[i_], b1, acc[i_][1], 0, 0, 0);
      }
      __builtin_amdgcn_s_setprio(0);
      __builtin_amdgcn_s_barrier();
    }
    // ---- ph3: reads u3 (B c2,c3); stage kt+1.u2 ----
    if (st1) STAGE8(2, kt+1);
    {
      s16x8 b2 = LDSRD(3, wn*64 + 32 + lr);
      s16x8 b3 = LDSRD(3, wn*64 + 48 + lr);
      __builtin_amdgcn_s_barrier();
      asm volatile("s_waitcnt lgkmcnt(0)" ::: "memory");
      __builtin_amdgcn_s_setprio(1);
      #pragma unroll
      for (int i_ = 0; i_ < 8; ++i_){
        acc[i_][2] = __builtin_amdgcn_mfma_f32_16x16x32_bf16(afp[i_], b2, acc[i_][2], 0, 0, 0);
        acc[i_][3] = __builtin_amdgcn_mfma_f32_16x16x32_bf16(afp[i_], b3, acc[i_][3], 0, 0, 0);
      }
      __builtin_amdgcn_s_setprio(0);
      if (st1) asm volatile("s_waitcnt vmcnt(2)" ::: "memory");  // retire kt+1.u0,u1
      __builtin_amdgcn_s_barrier();
    }
  }

  if (FUSE == 0){
    short* C = (short*)Cv;
    #pragma unroll
    for (int i = 0; i < 8; ++i){
      int row0 = bm0 + wm*128 + i*16 + lg*4;
      #pragma unroll
      for (int j = 0; j < 4; ++j){
        int col = bn0 + wn*64 + j*16 + lr;
        #pragma unroll
        for (int r = 0; r < 4; ++r) C[(size_t)(row0 + r)*N + col] = f2bf(acc[i][j][r]);
      }
    }
  } else if (FUSE == 1){
    short* C = (short*)Cv;
    const int Nh = N >> 1;
    #pragma unroll
    for (int i = 0; i < 8; ++i){
      int row0 = bm0 + wm*128 + i*16 + lg*4;
      #pragma unroll
      for (int jp = 0; jp < 2; ++jp){
        int col = (bn0 >> 1) + wn*32 + jp*16 + lr;
        #pragma unroll
        for (int r = 0; r < 4; ++r){
          float u = acc[i][jp*2][r], g = acc[i][jp*2+1][r];
          float val = u / (1.f + __expf(-u)) * g;
          C[(size_t)(row0 + r)*Nh + col] = f2bf(val);
        }
      }
    }
  } else if (FUSE == 2){
    short* C = (short*)Cv + (size_t)split*M*N;
    #pragma unroll
    for (int i = 0; i < 8; ++i){
      int row0 = bm0 + wm*128 + i*16 + lg*4;
      #pragma unroll
      for (int j = 0; j < 4; ++j){
        int col = bn0 + wn*64 + j*16 + lr;
        #pragma unroll
        for (int r = 0; r < 4; ++r) C[(size_t)(row0 + r)*N + col] = f2bf(acc[i][j][r]);
      }
    }
  } else {
    const int part = bn0 >> 10;
    const int colb = bn0 & 1023;
    const int h = (colb + wn*64) >> 6;
    if (part < 2){
      short* dst = (part == 0) ? Qo : Ko;
      const float qs = (part == 0) ? 0.1803368801111204f : 1.0f; // 0.125*log2(e)
      #pragma unroll
      for (int i = 0; i < 8; ++i){
        int row0 = bm0 + wm*128 + i*16 + lg*4;
        #pragma unroll
        for (int jh = 0; jh < 2; ++jh){
          int d = jh*16 + lr;
          #pragma unroll
          for (int r = 0; r < 4; ++r){
            int tg = row0 + r;
            int bb = tg >> 11, tt = tg & 2047;
            float c = cosb[tt*64 + d], s = sinb[tt*64 + d];
            float x0 = acc[i][jh][r], x1 = acc[i][jh+2][r];
            float y0 = (x0*c - x1*s)*qs;
            float y1 = (x1*c + x0*s)*qs;
            size_t o = ((size_t)(bb*CT + tt)*CNH + h)*CHD;
            dst[o + d]      = f2bf(y0);
            dst[o + d + 32] = f2bf(y1);
          }
        }
      }
    } else {
      #pragma unroll
      for (int i = 0; i < 8; ++i){
        int row0 = bm0 + wm*128 + i*16 + lg*4;
        int bb = row0 >> 11, t0 = row0 & 2047;
        #pragma unroll
        for (int j = 0; j < 4; ++j){
          int d = j*16 + lr;
          short4 pk;
          pk.x = f2bf(acc[i][j][0]); pk.y = f2bf(acc[i][j][1]);
          pk.z = f2bf(acc[i][j][2]); pk.w = f2bf(acc[i][j][3]);
          *(short4*)&Vo[((size_t)(bb*CNH + h)*CHD + d)*CT + t0] = pk;
        }
      }
    }
  }
}

// ---------------- causal flash attention v3 (round-13 proven) ----------------
__global__ __launch_bounds__(256) void attn_kernel(const short* __restrict__ Q,
                                                   const short* __restrict__ Kb,
                                                   const short* __restrict__ Vt,
                                                   short* __restrict__ O){
  __shared__ __align__(16) short Kl[2][64*72];
  __shared__ __align__(16) short Vl[2][64*72];
  __shared__ __align__(16) short Pl[4][16*72];
  const int tid = threadIdx.x, lane = tid & 63, w = tid >> 6;
  const int qpair = blockIdx.x;          // 0..15
  const int h = blockIdx.y, b = blockIdx.z;
  const int lr = lane & 15, lg = lane >> 4;

  const short* gK = Kb + (size_t)b*CT*CD + h*CHD;
  const short* gV = Vt + (size_t)(b*CNH + h)*CHD*CT;
  const int srow0 = tid >> 3, scol = (tid & 7)*8;

  #pragma unroll 1
  for (int half = 0; half < 2; ++half){
    const int qt = half ? qpair : (31 - qpair);
    const int wq0 = qt*64 + w*16;
    const int jmax = qt + 1;

    s16x8 qf0, qf1;
    {
      const short* qp = Q + ((size_t)(b*CT + wq0 + lr)*CNH + h)*CHD + lg*8;
      qf0 = *(const s16x8*)qp;
      qf1 = *(const s16x8*)(qp + 32);
    }
    f32x4 oacc[4];
    #pragma unroll
    for (int dt = 0; dt < 4; ++dt) oacc[dt] = (f32x4){0.f,0.f,0.f,0.f};
    float m_r = -1e30f, l_r = 0.f;

    #pragma unroll
    for (int p = 0; p < 2; ++p){
      int row = srow0 + p*32;
      *(s16x8*)&Kl[0][row*72 + scol] = *(const s16x8*)(gK + (size_t)row*CD + scol);
      *(s16x8*)&Vl[0][row*72 + scol] = *(const s16x8*)(gV + (size_t)row*CT + scol);
    }
    __syncthreads();

    #pragma unroll 1
    for (int j = 0; j < jmax; ++j){
      const int kv0 = j*64;
      const int buf = j & 1;
      s16x8 nk[2], nv[2];
      const bool havenext = (j + 1 < jmax);
      if (havenext){
        const int kv1 = kv0 + 64;
        #pragma unroll
        for (int p = 0; p < 2; ++p){
          int row = srow0 + p*32;
          nk[p] = *(const s16x8*)(gK + (size_t)(kv1 + row)*CD + scol);
          nv[p] = *(const s16x8*)(gV + (size_t)row*CT + kv1 + scol);
        }
      }

      if (kv0 < wq0 + 16){
        f32x4 sc[4];
        __builtin_amdgcn_s_setprio(1);
        #pragma unroll
        for (int nt = 0; nt < 4; ++nt){
          s16x8 k0 = *(const s16x8*)&Kl[buf][(nt*16 + lr)*72 + lg*8];
          s16x8 k1 = *(const s16x8*)&Kl[buf][(nt*16 + lr)*72 + 32 + lg*8];
          f32x4 z = (f32x4){0.f,0.f,0.f,0.f};
          z = __builtin_amdgcn_mfma_f32_16x16x32_bf16(k0, qf0, z, 0, 0, 0);
          z = __builtin_amdgcn_mfma_f32_16x16x32_bf16(k1, qf1, z, 0, 0, 0);
          sc[nt] = z;
        }
        __builtin_amdgcn_s_setprio(0);
        if (kv0 + 64 > wq0){
          #pragma unroll
          for (int nt = 0; nt < 4; ++nt)
            #pragma unroll
            for (int r = 0; r < 4; ++r)
              if (kv0 + nt*16 + lg*4 + r > wq0 + lr) sc[nt][r] = -1e30f;
        }
        float pmax = sc[0][0];
        #pragma unroll
        for (int nt = 0; nt < 4; ++nt)
          #pragma unroll
          for (int r = 0; r < 4; ++r) pmax = fmaxf(pmax, sc[nt][r]);
        pmax = fmaxf(pmax, __shfl_xor(pmax, 16));
        pmax = fmaxf(pmax, __shfl_xor(pmax, 32));
        if (!__all(pmax - m_r <= 10.f)){
          float mn = fmaxf(m_r, pmax);
          float corr = __builtin_amdgcn_exp2f(m_r - mn);
          m_r = mn;
          l_r *= corr;
          #pragma unroll
          for (int r = 0; r < 4; ++r){
            float c4 = __shfl(corr, lg*4 + r);
            #pragma unroll
            for (int dt = 0; dt < 4; ++dt) oacc[dt][r] *= c4;
          }
        }
        float rs = 0.f;
        #pragma unroll
        for (int nt = 0; nt < 4; ++nt)
          #pragma unroll
          for (int r = 0; r < 4; ++r){
            float pv = __builtin_amdgcn_exp2f(sc[nt][r] - m_r);
            sc[nt][r] = pv;
            rs += pv;
          }
        #pragma unroll
        for (int nt = 0; nt < 4; ++nt){
          uint2 pk;
          pk.x = cvtpk_bf16(sc[nt][0], sc[nt][1]);
          pk.y = cvtpk_bf16(sc[nt][2], sc[nt][3]);
          *(uint2*)&Pl[w][lr*72 + nt*16 + lg*4] = pk;
        }
        rs += __shfl_xor(rs, 16);
        rs += __shfl_xor(rs, 32);
        l_r += rs;
        s16x8 pa0 = *(const s16x8*)&Pl[w][lr*72 + lg*8];
        s16x8 pa1 = *(const s16x8*)&Pl[w][lr*72 + 32 + lg*8];
        __builtin_amdgcn_s_setprio(1);
        #pragma unroll
        for (int dt = 0; dt < 4; ++dt){
          s16x8 v0 = *(const s16x8*)&Vl[buf][(dt*16 + lr)*72 + lg*8];
          s16x8 v1 = *(const s16x8*)&Vl[buf][(dt*16 + lr)*72 + 32 + lg*8];
          oacc[dt] = __builtin_amdgcn_mfma_f32_16x16x32_bf16(pa0, v0, oacc[dt], 0, 0, 0);
          oacc[dt] = __builtin_amdgcn_mfma_f32_16x16x32_bf16(pa1, v1, oacc[dt], 0, 0, 0);
        }
        __builtin_amdgcn_s_setprio(0);
      }
      if (havenext){
        #pragma unroll
        for (int p = 0; p < 2; ++p){
          int row = srow0 + p*32;
          *(s16x8*)&Kl[buf^1][row*72 + scol] = nk[p];
          *(s16x8*)&Vl[buf^1][row*72 + scol] = nv[p];
        }
      }
      __syncthreads();
    }

    #pragma unroll
    for (int r = 0; r < 4; ++r){
      float lf = __shfl(l_r, lg*4 + r);
      float inv = 1.f / lf;
      int qrow = wq0 + lg*4 + r;
      #pragma unroll
      for (int dt = 0; dt < 4; ++dt)
        O[((size_t)(b*CT + qrow)*CNH + h)*CHD + dt*16 + lr] = f2bf(oacc[dt][r] * inv);
    }
  }
}

// ---------------- launch ----------------
extern "C" void kernel_launch(void* const* d_in, const int* in_sizes, int n_in,
                              void* d_out, int out_size, void* d_ws, size_t ws_size,
                              hipStream_t stream){
  (void)in_sizes; (void)n_in; (void)out_size; (void)ws_size;
  const float* x_processed = (const float*)d_in[0];
  const int*   boundaries  = (const int*)d_in[1];
  const float* x_residual  = (const float*)d_in[3];
  const float* cosb        = (const float*)d_in[4];
  const float* sinb        = (const float*)d_in[5];
  const float* wq          = (const float*)d_in[7];
  const float* wk          = (const float*)d_in[8];
  const float* wv          = (const float*)d_in[9];
  const float* wo          = (const float*)d_in[10];
  const float* attn_nw     = (const float*)d_in[11];
  const float* mlp_nw      = (const float*)d_in[12];
  const float* w1          = (const float*)d_in[13];
  const float* w3          = (const float*)d_in[14];
  const float* w2          = (const float*)d_in[15];
  const float* final_nw    = (const float*)d_in[16];

  char* p = (char*)d_ws;
  auto alloc = [&](size_t bytes)->char*{
    char* r = p; p += (bytes + 255) & ~(size_t)255; return r;
  };
  short* wqkvT = (short*)alloc((size_t)2*3072*1024*2);
  short* woT   = (short*)alloc((size_t)2*1024*1024*2);
  short* w13T  = (short*)alloc((size_t)2*8192*1024*2);
  short* w2T   = (short*)alloc((size_t)2*1024*4096*2);
  float* x     = (float*)alloc((size_t)4096*1024*4);
  short* hbuf  = (short*)alloc((size_t)4096*1024*2);
  short* qr    = (short*)alloc((size_t)4096*1024*2);
  short* kr    = (short*)alloc((size_t)4096*1024*2);
  short* vt    = (short*)alloc((size_t)4096*1024*2);
  short* obuf  = (short*)alloc((size_t)4096*1024*2);
  short* mbuf  = (short*)alloc((size_t)4096*4096*2);
  short* psum  = (short*)alloc((size_t)4*4096*1024*2);

  for (int l = 0; l < 2; ++l){
    size_t wOff = (size_t)l*1024*1024;
    wtrans_qkvo_kernel<<<dim3(16,16,4),256,0,stream>>>(wq + wOff, wk + wOff, wv + wOff, wo + wOff,
                                                       wqkvT + (size_t)l*3072*1024, woT + (size_t)l*1024*1024);
    wtrans_inter2_kernel<<<dim3(64,16,2),256,0,stream>>>(w1 + (size_t)l*1024*4096, w3 + (size_t)l*1024*4096,
                                                         w13T + (size_t)l*8192*1024);
    wtrans_kernel<<<dim3(16,64),256,0,stream>>>(w2 + (size_t)l*4096*1024, w2T + (size_t)l*1024*4096, 4096, 1024);
  }
  gather_rms_kernel<<<4096,256,0,stream>>>(x_processed, boundaries, x_residual, attn_nw, x, hbuf);
  for (int l = 0; l < 2; ++l){
    gemm8p<3><<<12*16,512,0,stream>>>(hbuf, wqkvT + (size_t)l*3072*1024, nullptr,
                                      qr, kr, vt, cosb, sinb,
                                      4096, 3072, 1024, 1024, 12, 16);
    attn_kernel<<<dim3(16,16,2),256,0,stream>>>(qr, kr, vt, obuf);
    gemm_splitk<<<8*32*4,256,0,stream>>>(obuf, woT + (size_t)l*1024*1024, psum,
                                         4096, 1024, 1024, 256, 8, 32);
    redrms_kernel<1,4><<<4096,256,0,stream>>>(x, psum, mlp_nw + l*1024, hbuf);
    gemm8p<1><<<32*16,512,0,stream>>>(hbuf, w13T + (size_t)l*8192*1024, mbuf,
                                      nullptr, nullptr, nullptr, nullptr, nullptr,
                                      4096, 8192, 1024, 1024, 32, 16);
    gemm8p<2><<<4*4*16,512,0,stream>>>(mbuf, w2T + (size_t)l*1024*4096, psum,
                                       nullptr, nullptr, nullptr, nullptr, nullptr,
                                       4096, 1024, 4096, 1024, 4, 16);
    if (l == 0) redrms_kernel<1,4><<<4096,256,0,stream>>>(x, psum, attn_nw + 1024, hbuf);
    else        redrms_kernel<0,4><<<4096,256,0,stream>>>(x, psum, final_nw, d_out);
  }
}